// Round 14
// baseline (299.362 us; speedup 1.0000x reference)
//
#include <hip/hip_runtime.h>
#include <hip/hip_bf16.h>

// Problem constants (fixed by reference): B=4, S=2048, DIN=DOUT=4096
constexpr int GM = 8192;   // B*S rows
constexpr int GN = 4096;   // DOUT
constexpr int GK = 4096;   // DIN

constexpr int BM = 256, BN = 256, BK = 64;
constexpr int NSTEP = GK / BK;   // 64 K-steps
constexpr int IT = NSTEP / 2;    // 32 iterations, 2 K-steps each
constexpr int LDS_BYTES = 2 * (BM + BN) * BK * 2;  // 131072 = 128 KiB

using bf16x8 = __attribute__((ext_vector_type(8))) __bf16;
using f32x4  = __attribute__((ext_vector_type(4))) float;

// -------------------- prep: A = bf16(x * in_scale) --------------------
__global__ __launch_bounds__(256) void prep_x_kernel(
    const float* __restrict__ x, const float* __restrict__ iscale,
    __bf16* __restrict__ A) {
  int e = (blockIdx.x * 256 + threadIdx.x) * 8;  // 8 elems/thread
  float4 v0 = *(const float4*)(x + e);
  float4 v1 = *(const float4*)(x + e + 4);
  int k = e & (GK - 1);
  float4 s0 = *(const float4*)(iscale + k);
  float4 s1 = *(const float4*)(iscale + k + 4);
  bf16x8 o;
  o[0] = (__bf16)(v0.x * s0.x);
  o[1] = (__bf16)(v0.y * s0.y);
  o[2] = (__bf16)(v0.z * s0.z);
  o[3] = (__bf16)(v0.w * s0.w);
  o[4] = (__bf16)(v1.x * s1.x);
  o[5] = (__bf16)(v1.y * s1.y);
  o[6] = (__bf16)(v1.z * s1.z);
  o[7] = (__bf16)(v1.w * s1.w);
  *(bf16x8*)(A + e) = o;
}

// -------------------- prep: Wb = bf16(sign(W)) --------------------
__device__ inline float sgnf(float v) {
  return (float)((v > 0.f) - (v < 0.f));
}

__global__ __launch_bounds__(256) void prep_w_kernel(
    const float* __restrict__ w, __bf16* __restrict__ Wb) {
  int e = (blockIdx.x * 256 + threadIdx.x) * 8;
  float4 v0 = *(const float4*)(w + e);
  float4 v1 = *(const float4*)(w + e + 4);
  bf16x8 o;
  o[0] = (__bf16)sgnf(v0.x);
  o[1] = (__bf16)sgnf(v0.y);
  o[2] = (__bf16)sgnf(v0.z);
  o[3] = (__bf16)sgnf(v0.w);
  o[4] = (__bf16)sgnf(v1.x);
  o[5] = (__bf16)sgnf(v1.y);
  o[6] = (__bf16)sgnf(v1.z);
  o[7] = (__bf16)sgnf(v1.w);
  *(bf16x8*)(Wb + e) = o;
}

// -------------------- GEMM: C[m][n] = sum_k A[m][k]*Wb[n][k] --------------------
// R13 base (m201-faithful 8-phase, de-pinned, bf16-C epilogue) with ONE
// change: QUAD issues kk OUTER, so the 16 MFMAs of a phase are two sweeps
// of 8 INDEPENDENT accumulators instead of 8 adjacent dependent pairs.
// Each acc register now has ~7 independent MFMAs (~35 cyc) between its two
// writes, covering MFMA latency; kk-inner paid latency (~16 cyc) per pair.
// Per-acc addition order is unchanged (kk=0 then kk=1) — numerics identical.
// Everything else identical to R13 (see its comments for the stage ring,
// vmcnt(6) retire-set proof, WAR analysis, swizzle, XCD chunking).
__device__ inline void gload16(const __bf16* g, const __bf16* l) {
  __builtin_amdgcn_global_load_lds(
      (const __attribute__((address_space(1))) void*)g,
      (__attribute__((address_space(3))) void*)l, 16, 0, 0);
}

#define PHASE_SYNC()                                    \
  __builtin_amdgcn_s_barrier();                         \
  asm volatile("s_waitcnt lgkmcnt(0)" ::: "memory");    \
  __builtin_amdgcn_sched_barrier(0);                    \
  __builtin_amdgcn_s_setprio(1);

#define PHASE_END()                                     \
  __builtin_amdgcn_s_setprio(0);                        \
  __builtin_amdgcn_s_barrier();

#define QUAD(AV, BV, MO, NO)                                                 \
  {                                                                          \
    _Pragma("unroll") for (int kk = 0; kk < 2; ++kk)                         \
      _Pragma("unroll") for (int mi = 0; mi < 4; ++mi)                       \
        _Pragma("unroll") for (int ni = 0; ni < 2; ++ni)                     \
            acc[(MO) + mi][(NO) + ni] =                                      \
                __builtin_amdgcn_mfma_f32_16x16x32_bf16(                     \
                    AV[mi][kk], BV[ni][kk], acc[(MO) + mi][(NO) + ni],       \
                    0, 0, 0);                                                \
  }

__global__ __launch_bounds__(512, 2) void gemm_bt(
    const __bf16* __restrict__ A, const __bf16* __restrict__ B,
    float* __restrict__ C) {
  extern __shared__ __bf16 lds[];  // 2 x 64 KiB buffers

  // Square XCD chunking (FETCH ~197 MB measured R3-R13)
  int bid = blockIdx.x;            // 0..511
  int x = bid & 7, idx = bid >> 3;
  int brow = ((x & 3) << 3) | (idx & 7);   // 0..31
  int bcol = ((x >> 2) << 3) | (idx >> 3); // 0..15

  int tid = threadIdx.x, wid = tid >> 6, lane = tid & 63;
  int wm = wid & 1, wn = wid >> 1;         // 2M x 4N waves
  int lrow = lane & 15, lkhi = lane >> 4;

  const __bf16* Ab = A + (size_t)(brow * BM) * GK;
  const __bf16* Bb = B + (size_t)(bcol * BN) * GK;
  const __bf16* Ab1 = Ab + (size_t)128 * GK;
  const __bf16* Bb1 = Bb + (size_t)128 * GK;

  // read-side swizzled chunk offsets (bytes within the 128-B row)
  int xr = lrow & 7;
  int offk0 = (lkhi ^ xr) * 16;        // kk=0 chunk
  int offk1 = ((4 + lkhi) ^ xr) * 16;  // kk=1 chunk
  const char* ldsc = (const char*)lds;
  // fragment byte bases within a buffer (regions: A0 0, A1 16K, B0 32K, B1 48K)
  int avbase = wm * 16384 + lrow * 128;                                // +mi*2048
  int bvbase = 32768 + (wn >> 1) * 16384 + ((wn & 1) * 64 + lrow) * 128;  // +ni*2048

  // stage-side: thread t writes bytes [t*16,t*16+16) of each 8-KiB half-region
  int grow = tid >> 3;                         // row within 64-row half
  int gcol = ((tid & 7) ^ (grow & 7)) * 8;     // pre-swizzled source col (elems)

  // stage ONE 128-row half-tile (2 x gload_lds) of K-step `kstep`
  auto STAGE = [&](const __bf16* srcbase, int kstep, int dstelem) {
    const __bf16* s = srcbase + (size_t)grow * GK + kstep * BK + gcol;
    const __bf16* d = lds + dstelem + tid * 8;
    gload16(s, d);
    gload16(s + (size_t)64 * GK, d + 4096);
  };

  f32x4 acc[8][4] = {};

  // prologue: step0 all 4 halves -> buf0; step1 {A0,B0,B1} -> buf1
  STAGE(Ab, 0, 0);
  STAGE(Ab1, 0, 8192);
  STAGE(Bb, 0, 16384);
  STAGE(Bb1, 0, 24576);
  STAGE(Ab, 1, 32768);        // buf1:A0
  STAGE(Bb, 1, 49152);        // buf1:B0
  STAGE(Bb1, 1, 57344);       // buf1:B1
  asm volatile("s_waitcnt vmcnt(6)" ::: "memory");  // step0 landed
  __builtin_amdgcn_s_barrier();

  for (int j = 0; j < IT; ++j) {
    int o = 2 * j + 1, n0 = 2 * j + 2, n1 = 2 * j + 3;
    bool full = (j < IT - 1);
    bf16x8 a0[4][2], a4[4][2], b0[2][2], b2[2][2];

    // ================= K-step 2j (buf0, byte 0) =================
    // P1: reads a0(8) + b0(4); stage (o):A1 -> buf1
#pragma unroll
    for (int mi = 0; mi < 4; ++mi) {
      a0[mi][0] = *(const bf16x8*)(ldsc + avbase + mi * 2048 + offk0);
      a0[mi][1] = *(const bf16x8*)(ldsc + avbase + mi * 2048 + offk1);
    }
#pragma unroll
    for (int ni = 0; ni < 2; ++ni) {
      b0[ni][0] = *(const bf16x8*)(ldsc + bvbase + ni * 2048 + offk0);
      b0[ni][1] = *(const bf16x8*)(ldsc + bvbase + ni * 2048 + offk1);
    }
    STAGE(Ab1, o, 40960);     // buf1:A1 (last read prev-iter P7; barrier-safe)
    asm volatile("s_waitcnt lgkmcnt(8)" ::: "memory");  // throttle 12-read burst
    PHASE_SYNC();
    QUAD(a0, b0, 0, 0);
    PHASE_END();

    // P2: reads b2(4)
#pragma unroll
    for (int ni = 0; ni < 2; ++ni) {
      b2[ni][0] = *(const bf16x8*)(ldsc + bvbase + (2 + ni) * 2048 + offk0);
      b2[ni][1] = *(const bf16x8*)(ldsc + bvbase + (2 + ni) * 2048 + offk1);
    }
    PHASE_SYNC();
    QUAD(a0, b2, 0, 2);
    PHASE_END();

    // P3: reads a4(8); stage (n0):B0,B1 -> buf0 (B last read P2)
#pragma unroll
    for (int mi = 0; mi < 4; ++mi) {
      a4[mi][0] = *(const bf16x8*)(ldsc + avbase + (4 + mi) * 2048 + offk0);
      a4[mi][1] = *(const bf16x8*)(ldsc + avbase + (4 + mi) * 2048 + offk1);
    }
    if (full) { STAGE(Bb, n0, 16384); STAGE(Bb1, n0, 24576); }
    PHASE_SYNC();
    QUAD(a4, b0, 4, 0);
    PHASE_END();

    // P4: stage (n0):A0 -> buf0 (A0 last read P3); vmcnt(6) retires step o
    if (full) STAGE(Ab, n0, 0);
    PHASE_SYNC();
    QUAD(a4, b2, 4, 2);
    __builtin_amdgcn_s_setprio(0);
    if (full) asm volatile("s_waitcnt vmcnt(6)" ::: "memory");
    else      asm volatile("s_waitcnt vmcnt(0)" ::: "memory");
    __builtin_amdgcn_s_barrier();

    // ================= K-step 2j+1 (buf1, byte 65536) =================
    // P5: reads a0(8) + b0(4); stage (n0):A1 -> buf0 (A1 last read P3)
#pragma unroll
    for (int mi = 0; mi < 4; ++mi) {
      a0[mi][0] = *(const bf16x8*)(ldsc + 65536 + avbase + mi * 2048 + offk0);
      a0[mi][1] = *(const bf16x8*)(ldsc + 65536 + avbase + mi * 2048 + offk1);
    }
#pragma unroll
    for (int ni = 0; ni < 2; ++ni) {
      b0[ni][0] = *(const bf16x8*)(ldsc + 65536 + bvbase + ni * 2048 + offk0);
      b0[ni][1] = *(const bf16x8*)(ldsc + 65536 + bvbase + ni * 2048 + offk1);
    }
    if (full) STAGE(Ab1, n0, 8192);
    asm volatile("s_waitcnt lgkmcnt(8)" ::: "memory");
    PHASE_SYNC();
    QUAD(a0, b0, 0, 0);
    PHASE_END();

    // P6: reads b2(4)
#pragma unroll
    for (int ni = 0; ni < 2; ++ni) {
      b2[ni][0] = *(const bf16x8*)(ldsc + 65536 + bvbase + (2 + ni) * 2048 + offk0);
      b2[ni][1] = *(const bf16x8*)(ldsc + 65536 + bvbase + (2 + ni) * 2048 + offk1);
    }
    PHASE_SYNC();
    QUAD(a0, b2, 0, 2);
    PHASE_END();

    // P7: reads a4(8); stage (n1):B0,B1 -> buf1 (B last read P6)
#pragma unroll
    for (int mi = 0; mi < 4; ++mi) {
      a4[mi][0] = *(const bf16x8*)(ldsc + 65536 + avbase + (4 + mi) * 2048 + offk0);
      a4[mi][1] = *(const bf16x8*)(ldsc + 65536 + avbase + (4 + mi) * 2048 + offk1);
    }
    if (full) { STAGE(Bb, n1, 49152); STAGE(Bb1, n1, 57344); }
    PHASE_SYNC();
    QUAD(a4, b0, 4, 0);
    PHASE_END();

    // P8: stage (n1):A0 -> buf1 (A0 last read P7); vmcnt(6) retires step n0
    if (full) STAGE(Ab, n1, 32768);
    PHASE_SYNC();
    QUAD(a4, b2, 4, 2);
    __builtin_amdgcn_s_setprio(0);
    if (full) asm volatile("s_waitcnt vmcnt(6)" ::: "memory");
    else      asm volatile("s_waitcnt vmcnt(0)" ::: "memory");
    __builtin_amdgcn_s_barrier();
  }

  // epilogue: h as bf16 into the second half of each f32 output row slot.
  // C/D layout (16x16x32 bf16): col = lane&15, row = (lane>>4)*4 + r
  int crow0 = brow * BM + wm * 128;
  int ccol0 = bcol * BN + wn * 64;
  char* Cb = (char*)C;
#pragma unroll
  for (int mi = 0; mi < 8; ++mi)
#pragma unroll
    for (int ni = 0; ni < 4; ++ni) {
      int col = ccol0 + ni * 16 + lrow;
#pragma unroll
      for (int r = 0; r < 4; ++r) {
        int row = crow0 + mi * 16 + lkhi * 4 + r;
        *(__bf16*)(Cb + (size_t)row * 16384 + 8192 + col * 2) =
            (__bf16)acc[mi][ni][r];
      }
    }
}

// ---------- fused out_scale/bias + LayerNorm: bf16 h (2nd half-slot) -> f32 ----------
__global__ __launch_bounds__(256) void ln_fuse(
    float* __restrict__ out, const float* __restrict__ os,
    const float* __restrict__ bs, const float* __restrict__ g,
    const float* __restrict__ be) {
  constexpr int N = GN;  // 4096
  int row = blockIdx.x;
  const __bf16* hr = (const __bf16*)((const char*)out + (size_t)row * 16384 + 8192);
  float* orow = out + (size_t)row * N;
  int t = threadIdx.x;

  float v[16];
  float sum = 0.f, ssq = 0.f;
#pragma unroll
  for (int c = 0; c < 2; ++c) {
    int idx = c * 2048 + t * 8;       // 8 bf16 per chunk, 2 chunks/thread
    bf16x8 hv = *(const bf16x8*)(hr + idx);
    float4 s0 = *(const float4*)(os + idx);
    float4 s1 = *(const float4*)(os + idx + 4);
    float4 b0 = *(const float4*)(bs + idx);
    float4 b1 = *(const float4*)(bs + idx + 4);
#pragma unroll
    for (int j = 0; j < 4; ++j) {
      float a = (float)hv[j] * (&s0.x)[j] + (&b0.x)[j];
      v[c * 8 + j] = a;
      sum += a; ssq += a * a;
    }
#pragma unroll
    for (int j = 0; j < 4; ++j) {
      float a = (float)hv[4 + j] * (&s1.x)[j] + (&b1.x)[j];
      v[c * 8 + 4 + j] = a;
      sum += a; ssq += a * a;
    }
  }

  // wave64 reduce
#pragma unroll
  for (int off = 32; off > 0; off >>= 1) {
    sum += __shfl_down(sum, off);
    ssq += __shfl_down(ssq, off);
  }
  __shared__ float rs[8];
  int wid = t >> 6, lane = t & 63;
  if (lane == 0) { rs[wid] = sum; rs[4 + wid] = ssq; }
  __syncthreads();   // also separates all h reads from the in-place writes
  sum = rs[0] + rs[1] + rs[2] + rs[3];
  ssq = rs[4] + rs[5] + rs[6] + rs[7];

  float mean = sum * (1.f / N);
  float var = ssq * (1.f / N) - mean * mean;
  float rstd = rsqrtf(var + 1e-5f);

#pragma unroll
  for (int c = 0; c < 2; ++c) {
    int idx = c * 2048 + t * 8;
    float4 g0 = *(const float4*)(g + idx);
    float4 g1 = *(const float4*)(g + idx + 4);
    float4 e0 = *(const float4*)(be + idx);
    float4 e1 = *(const float4*)(be + idx + 4);
    float4 o0, o1;
#pragma unroll
    for (int j = 0; j < 4; ++j) {
      (&o0.x)[j] = (v[c * 8 + j] - mean) * rstd * (&g0.x)[j] + (&e0.x)[j];
      (&o1.x)[j] = (v[c * 8 + 4 + j] - mean) * rstd * (&g1.x)[j] + (&e1.x)[j];
    }
    *(float4*)(orow + idx) = o0;
    *(float4*)(orow + idx + 4) = o1;
  }
}

extern "C" void kernel_launch(void* const* d_in, const int* in_sizes, int n_in,
                              void* d_out, int out_size, void* d_ws, size_t ws_size,
                              hipStream_t stream) {
  const float* x      = (const float*)d_in[0];  // [4,2048,4096]
  const float* w      = (const float*)d_in[1];  // [4096,4096]
  const float* iscale = (const float*)d_in[2];  // [4096]
  const float* oscale = (const float*)d_in[3];  // [4096]
  const float* bias   = (const float*)d_in[4];  // [4096]
  const float* gamma  = (const float*)d_in[5];  // [4096]
  const float* beta   = (const float*)d_in[6];  // [4096]
  float* out = (float*)d_out;                   // [8192,4096] f32

  __bf16* Abf = (__bf16*)d_ws;                                   // 67 MB
  __bf16* Wbf = (__bf16*)((char*)d_ws + (size_t)GM * GK * 2);    // 33.5 MB

  (void)hipFuncSetAttribute((const void*)gemm_bt,
                            hipFuncAttributeMaxDynamicSharedMemorySize, LDS_BYTES);

  prep_x_kernel<<<(GM * GK) / (256 * 8), 256, 0, stream>>>(x, iscale, Abf);
  prep_w_kernel<<<(GN * GK) / (256 * 8), 256, 0, stream>>>(w, Wbf);
  gemm_bt<<<(GM / BM) * (GN / BN), 512, LDS_BYTES, stream>>>(Abf, Wbf, out);
  ln_fuse<<<GM, 256, 0, stream>>>(out, oscale, bias, gamma, beta);
}